// Round 1
// baseline (1448.124 us; speedup 1.0000x reference)
//
#include <hip/hip_runtime.h>

// MeshUnpool: B=8, C=128, E_OLD=48000, U=8000, E_NEW=72000.
// Scatter formulation: every output column written exactly once (indices come
// from a permutation), so no zero-init / RMW needed.
//
// Block layout: grid = (ceil(T_PER_B/256), B). Each thread owns one source
// "work item" t for batch b and loops over all 128 channels, so the 5 index
// loads + 6 weight loads happen once per 128 channel-iterations (registers).
//   t < U            : pair thread, reads feat[c][t] and feat[c][t+U],
//                      writes 5 scattered outputs.
//   t in [U, 40000)  : copy thread for e = t+U in [2U, E_OLD),
//                      writes 1 scattered output.

constexpr int B_     = 8;
constexpr int C_     = 128;
constexpr int E_OLD_ = 48000;
constexpr int U_     = 8000;
constexpr int E_NEW_ = E_OLD_ + 3 * U_;          // 72000
constexpr int T_PER_B = U_ + (E_OLD_ - 2 * U_);  // 40000

__global__ __launch_bounds__(256)
void MeshUnpool_52261162058491_kernel(const float* __restrict__ feat,
                                      const float* __restrict__ w,
                                      const int*   __restrict__ old_idx,
                                      const int*   __restrict__ new_idx,
                                      const int*   __restrict__ new_left,
                                      const int*   __restrict__ new_right,
                                      float*       __restrict__ out) {
    const int b = blockIdx.y;
    const int t = blockIdx.x * blockDim.x + threadIdx.x;
    if (t >= T_PER_B) return;

    const float* fb = feat + (size_t)b * C_ * E_OLD_;
    float*       ob = out  + (size_t)b * C_ * E_NEW_;

    if (t < U_) {
        const int u   = t;
        const int jl  = old_idx[b * E_OLD_ + u];
        const int jr  = old_idx[b * E_OLD_ + U_ + u];
        const int jn  = new_idx [b * U_ + u];
        const int jnl = new_left[b * U_ + u];
        const int jnr = new_right[b * U_ + u];

        const float* wp = w + ((size_t)b * U_ + u) * 6;
        const float lw0 = wp[0], lw1 = wp[1], lw2 = wp[2];
        const float rw0 = wp[3], rw1 = wp[4], rw2 = wp[5];

        const float* fl_p = fb + u;
        const float* fr_p = fb + U_ + u;
        float*       orow = ob;
        #pragma unroll 4
        for (int c = 0; c < C_; ++c) {
            const float fl = *fl_p;
            const float fr = *fr_p;
            orow[jl]  = fl * lw0;
            orow[jnl] = fl * lw1;
            orow[jr]  = fr * rw0;
            orow[jnr] = fr * rw1;
            orow[jn]  = 0.5f * (fl * lw2 + fr * rw2);
            fl_p += E_OLD_;
            fr_p += E_OLD_;
            orow += E_NEW_;
        }
    } else {
        const int e = t + U_;  // [2U, E_OLD)
        const int j = old_idx[b * E_OLD_ + e];

        const float* fp   = fb + e;
        float*       orow = ob;
        #pragma unroll 8
        for (int c = 0; c < C_; ++c) {
            orow[j] = *fp;
            fp   += E_OLD_;
            orow += E_NEW_;
        }
    }
}

extern "C" void kernel_launch(void* const* d_in, const int* in_sizes, int n_in,
                              void* d_out, int out_size, void* d_ws, size_t ws_size,
                              hipStream_t stream) {
    const float* feat      = (const float*)d_in[0];
    const float* w         = (const float*)d_in[1];
    const int*   old_idx   = (const int*)  d_in[2];
    // d_in[3] = left_idx  (== old_idx[:, :U])   — redundant, unused
    // d_in[4] = right_idx (== old_idx[:, U:2U]) — redundant, unused
    const int*   new_idx   = (const int*)  d_in[5];
    const int*   new_left  = (const int*)  d_in[6];
    const int*   new_right = (const int*)  d_in[7];
    float*       out       = (float*)d_out;

    dim3 block(256);
    dim3 grid((T_PER_B + 255) / 256, B_);
    MeshUnpool_52261162058491_kernel<<<grid, block, 0, stream>>>(
        feat, w, old_idx, new_idx, new_left, new_right, out);
}

// Round 2
// 998.413 us; speedup vs baseline: 1.4504x; 1.4504x over previous
//
#include <hip/hip_runtime.h>

// MeshUnpool — gather formulation.
// R1 scatter kernel suffered 8x write amplification (WRITE_SIZE 2.42 GB vs
// 295 MB ideal): random dword scatters -> partial-line L2 writebacks.
// Fix: precompute per-output-column map {s0, s1, w0, w1} (kernel 1, scatter of
// 9.2 MB into d_ws), then gather kernel 2 with fully coalesced output stores:
//   out[b][c][j] = w0*feat[b][c][s0] + w1*feat[b][c][s1]
// Single-source columns use s1=s0, w1=0 (second gather hits same line).

constexpr int B_     = 8;
constexpr int C_     = 128;
constexpr int E_OLD_ = 48000;
constexpr int U_     = 8000;
constexpr int E_NEW_ = E_OLD_ + 3 * U_;          // 72000
constexpr int T_PER_B = U_ + (E_OLD_ - 2 * U_);  // 40000

__device__ __forceinline__ int4 pack_map(int s0, int s1, float w0, float w1) {
    return make_int4(s0, s1, __float_as_int(w0), __float_as_int(w1));
}

// Kernel 1: build the inverse map. Scattered 16B writes, ~9.2 MB total.
__global__ __launch_bounds__(256)
void build_map_kernel(const float* __restrict__ w,
                      const int*   __restrict__ old_idx,
                      const int*   __restrict__ new_idx,
                      const int*   __restrict__ new_left,
                      const int*   __restrict__ new_right,
                      int4*        __restrict__ map) {
    const int b = blockIdx.y;
    const int t = blockIdx.x * blockDim.x + threadIdx.x;
    if (t >= T_PER_B) return;

    int4* mb = map + (size_t)b * E_NEW_;

    if (t < U_) {
        const int u   = t;
        const int jl  = old_idx [b * E_OLD_ + u];
        const int jr  = old_idx [b * E_OLD_ + U_ + u];
        const int jn  = new_idx [b * U_ + u];
        const int jnl = new_left [b * U_ + u];
        const int jnr = new_right[b * U_ + u];

        const float* wp = w + ((size_t)b * U_ + u) * 6;
        const float lw0 = wp[0], lw1 = wp[1], lw2 = wp[2];
        const float rw0 = wp[3], rw1 = wp[4], rw2 = wp[5];

        mb[jl]  = pack_map(u,       u,       lw0,        0.f);
        mb[jnl] = pack_map(u,       u,       lw1,        0.f);
        mb[jr]  = pack_map(U_ + u,  U_ + u,  rw0,        0.f);
        mb[jnr] = pack_map(U_ + u,  U_ + u,  rw1,        0.f);
        mb[jn]  = pack_map(u,       U_ + u,  0.5f * lw2, 0.5f * rw2);
    } else {
        const int e = t + U_;  // [2U, E_OLD)
        const int j = old_idx[b * E_OLD_ + e];
        mb[j] = pack_map(e, e, 1.0f, 0.f);
    }
}

// Kernel 2: gather. One thread per output column j; loop over channels.
// Stores coalesced (full-line streaming); feature reads are lane-scattered
// gathers over a 192 KB row window, served by L2/L3.
// Grid is 1D with b = blockIdx.x % 8: under round-robin block->XCD dispatch
// each XCD's L2 predominantly serves one batch's feature rows.
constexpr int K2_BLOCK   = 256;
constexpr int CHUNKS_PER_B = (E_NEW_ + K2_BLOCK - 1) / K2_BLOCK;  // 282

__global__ __launch_bounds__(K2_BLOCK)
void gather_kernel(const float* __restrict__ feat,
                   const int4*  __restrict__ map,
                   float*       __restrict__ out) {
    const int b     = blockIdx.x % B_;
    const int chunk = blockIdx.x / B_;
    const int j     = chunk * K2_BLOCK + threadIdx.x;
    if (j >= E_NEW_) return;

    const int4 m  = map[(size_t)b * E_NEW_ + j];
    const int  s0 = m.x;
    const int  s1 = m.y;
    const float w0 = __int_as_float(m.z);
    const float w1 = __int_as_float(m.w);

    const float* fb = feat + (size_t)b * C_ * E_OLD_;
    float*       ob = out  + (size_t)b * C_ * E_NEW_ + j;

    #pragma unroll 4
    for (int c = 0; c < C_; ++c) {
        const float f0 = fb[s0];
        const float f1 = fb[s1];
        *ob = w0 * f0 + w1 * f1;
        fb += E_OLD_;
        ob += E_NEW_;
    }
}

extern "C" void kernel_launch(void* const* d_in, const int* in_sizes, int n_in,
                              void* d_out, int out_size, void* d_ws, size_t ws_size,
                              hipStream_t stream) {
    const float* feat      = (const float*)d_in[0];
    const float* w         = (const float*)d_in[1];
    const int*   old_idx   = (const int*)  d_in[2];
    // d_in[3] = left_idx  (== old_idx[:, :U])   — unused
    // d_in[4] = right_idx (== old_idx[:, U:2U]) — unused
    const int*   new_idx   = (const int*)  d_in[5];
    const int*   new_left  = (const int*)  d_in[6];
    const int*   new_right = (const int*)  d_in[7];
    float*       out       = (float*)d_out;
    int4*        map       = (int4*)d_ws;   // 8*72000*16 B = 9.216 MB

    {
        dim3 block(256);
        dim3 grid((T_PER_B + 255) / 256, B_);
        build_map_kernel<<<grid, block, 0, stream>>>(
            w, old_idx, new_idx, new_left, new_right, map);
    }
    {
        dim3 block(K2_BLOCK);
        dim3 grid(CHUNKS_PER_B * B_);
        gather_kernel<<<grid, block, 0, stream>>>(feat, map, out);
    }
}